// Round 6
// baseline (405.619 us; speedup 1.0000x reference)
//
#include <hip/hip_runtime.h>

// Problem constants
#define NTOK 343   // tokens per window (7*7*7)
#define NPAD 352   // 22 * 16
#define CEMB 192
#define NH   6
#define HD   32
#define NB   256
#define NWIN 64
#define FPLANE 123904   // fragment-plane stride in shorts: 22*11*2*64*4

typedef __attribute__((ext_vector_type(8))) short short8;   // 8 x bf16 bits
typedef __attribute__((ext_vector_type(4))) float f32x4;
typedef __attribute__((ext_vector_type(4))) unsigned int uint4v;
typedef __attribute__((ext_vector_type(2))) unsigned int uint2v;

__device__ __forceinline__ unsigned short f2bf(float f) {
    unsigned int u = __builtin_bit_cast(unsigned int, f);
    u += 0x7fffu + ((u >> 16) & 1u);          // round-to-nearest-even
    return (unsigned short)(u >> 16);
}
__device__ __forceinline__ float bf2f(unsigned short h) {
    unsigned int u = ((unsigned int)h) << 16;
    return __builtin_bit_cast(float, u);
}
__device__ __forceinline__ short8 pack8(float4 f0, float4 f1) {
    short8 r;
    r[0] = (short)f2bf(f0.x); r[1] = (short)f2bf(f0.y);
    r[2] = (short)f2bf(f0.z); r[3] = (short)f2bf(f0.w);
    r[4] = (short)f2bf(f1.x); r[5] = (short)f2bf(f1.y);
    r[6] = (short)f2bf(f1.z); r[7] = (short)f2bf(f1.w);
    return r;
}
__device__ __forceinline__ unsigned int cvt_pk_bf16(float lo, float hi) {
    unsigned int r;
    asm("v_cvt_pk_bf16_f32 %0, %1, %2" : "=v"(r) : "v"(lo), "v"(hi));
    return r;
}

#define LOG2E 1.4426950408889634f

// ---------------- prep: weights -> bf16 AND biasF fragments (merged) ----------------
// blocks 0..575: weights (scale*log2e folded into qw)
// blocks 576..1303: biasF[h][mt][ch][t][lane][r] in MFMA-fragment order
__global__ void prep_wb(const float* __restrict__ qw, const float* __restrict__ kvw,
                        const float* __restrict__ pw, const float* __restrict__ table,
                        const int* __restrict__ rel,
                        unsigned short* __restrict__ qwb, unsigned short* __restrict__ kvwb,
                        unsigned short* __restrict__ pwb, unsigned short* __restrict__ biasF) {
    if (blockIdx.x < 576) {
        const float scale = 0.17677669529663689f * LOG2E;   // 32^-0.5 * log2(e)
        int idx = blockIdx.x * 256 + threadIdx.x;
        if (idx < 36864)        qwb[idx] = f2bf(qw[idx] * scale);
        else if (idx < 110592)  kvwb[idx - 36864] = f2bf(kvw[idx - 36864]);
        else if (idx < 147456)  pwb[idx - 110592] = f2bf(pw[idx - 110592]);
    } else {
        int idx = (blockIdx.x - 576) * 256 + threadIdx.x;   // 6*22*11*2*64 = 728*256 exact
        int lane = idx & 63;
        int rest = idx >> 6;
        int t = rest & 1; rest >>= 1;
        int ch = rest % 11; rest /= 11;
        int mt = rest % 22; int h = rest / 22;
        int q = mt * 16 + (lane & 15);
        int k0 = ch * 32 + t * 16 + ((lane >> 4) << 2);
        ushort4 out;
#pragma unroll
        for (int r = 0; r < 4; r++) {
            int k = k0 + r;
            float v = (q < NTOK && k < NTOK) ? table[rel[q * NTOK + k] * NH + h] * LOG2E : 0.f;
            ((unsigned short*)&out)[r] = f2bf(v);
        }
        *(ushort4*)(biasF + (size_t)idx * 4) = out;
    }
}

// ---------------- prep: maskF in MFMA-fragment order; pad keys = -60000 ----------------
__global__ void prep_maskF(const float* __restrict__ mask, unsigned short* __restrict__ maskF) {
    int idx = blockIdx.x * 256 + threadIdx.x;       // 64*22*11*2*64 = 7744*256 exact
    int lane = idx & 63;
    int rest = idx >> 6;
    int t = rest & 1; rest >>= 1;
    int ch = rest % 11; rest /= 11;
    int mt = rest % 22; int w = rest / 22;
    int q = mt * 16 + (lane & 15);
    int k0 = ch * 32 + t * 16 + ((lane >> 4) << 2);
    ushort4 out;
#pragma unroll
    for (int r = 0; r < 4; r++) {
        int k = k0 + r;
        float v;
        if (k >= NTOK) v = -60000.f;                 // pad key: exp2 -> 0, no branch in attn
        else if (q < NTOK) v = mask[((size_t)w * NTOK + q) * NTOK + k] * LOG2E;
        else v = 0.f;                                // pad q rows: stores are guarded anyway
        ((unsigned short*)&out)[r] = f2bf(v);
    }
    *(ushort4*)(maskF + (size_t)idx * 4) = out;
}

// ---------------- merged QKV projection GEMM ----------------
// 512 blocks: gid 0..255 -> Q for b=gid; gid 256..511 -> K+V for b=gid-256.
// Sequential dispatch puts one Q block + one KV block per CU (2 blocks/CU,
// 76.8 KB LDS each) instead of two serial 1-block/CU launches.
__global__ __launch_bounds__(512, 2)
void qkv_kernel(const float* __restrict__ x_in, const float* __restrict__ x_cross,
                const unsigned short* __restrict__ qwb, const unsigned short* __restrict__ kvwb,
                unsigned short* __restrict__ Qb, unsigned short* __restrict__ Kb,
                unsigned short* __restrict__ Vtb) {
    extern __shared__ char smem[];
    unsigned short* Ws = (unsigned short*)smem;      // [192][200] padded
    const int tid = threadIdx.x;
    const int wave = tid >> 6, lane = tid & 63;
    const int quad = lane >> 4, l16 = lane & 15;
    const f32x4 zero4 = {0.f, 0.f, 0.f, 0.f};

    if (blockIdx.x < NB) {
        // ---------------- Q path ----------------
        const int b = blockIdx.x;
        for (int i = tid; i < 4608; i += 512) {
            int r = i / 24, c8 = i - r * 24;
            *(short8*)(Ws + r * 200 + c8 * 8) = *(const short8*)(qwb + (size_t)r * CEMB + c8 * 8);
        }
        __syncthreads();
        for (int mi = 0; mi < 3; mi++) {
            int mt = wave + (mi << 3);
            if (mt >= 22) continue;            // wave-uniform
            int row = mt * 16 + l16;
            f32x4 acc[12];
#pragma unroll
            for (int nt = 0; nt < 12; nt++) acc[nt] = zero4;
#pragma unroll
            for (int kc = 0; kc < 6; kc++) {
                short8 a = {};
                if (row < NTOK) {
                    const float* xp = x_in + ((size_t)b * NTOK + row) * CEMB + kc * 32 + (quad << 3);
                    a = pack8(*(const float4*)xp, *(const float4*)(xp + 4));
                }
#pragma unroll
                for (int nt = 0; nt < 12; nt++) {
                    const short8 bf = *(const short8*)(Ws + (nt * 16 + l16) * 200 + kc * 32 + (quad << 3));
                    acc[nt] = __builtin_amdgcn_mfma_f32_16x16x32_bf16(a, bf, acc[nt], 0, 0, 0);
                }
            }
            unsigned short* dst = Qb + (size_t)b * NPAD * CEMB;
#pragma unroll
            for (int nt = 0; nt < 12; nt++) {
#pragma unroll
                for (int r = 0; r < 4; r++) {
                    int m = mt * 16 + (quad << 2) + r;
                    dst[(size_t)m * CEMB + nt * 16 + l16] = f2bf(acc[nt][r]);
                }
            }
        }
    } else {
        // ---------------- K+V path (x_cross read once, A-frags held in regs) ----------------
        const int b = blockIdx.x - NB;
        for (int i = tid; i < 4608; i += 512) {
            int r = i / 24, c8 = i - r * 24;
            *(short8*)(Ws + r * 200 + c8 * 8) = *(const short8*)(kvwb + (size_t)r * CEMB + c8 * 8);
        }
        short8 a[3][6];
#pragma unroll
        for (int mi = 0; mi < 3; mi++) {
            int mt = wave + (mi << 3);
            int row = mt * 16 + l16;
#pragma unroll
            for (int kc = 0; kc < 6; kc++) {
                a[mi][kc] = (short8){};
                if (mt < 22 && row < NTOK) {
                    const float* xp = x_cross + ((size_t)b * NTOK + row) * CEMB + kc * 32 + (quad << 3);
                    a[mi][kc] = pack8(*(const float4*)xp, *(const float4*)(xp + 4));
                }
            }
        }
        __syncthreads();
        // K pass
#pragma unroll
        for (int mi = 0; mi < 3; mi++) {
            int mt = wave + (mi << 3);
            if (mt >= 22) continue;
            f32x4 acc[12];
#pragma unroll
            for (int nt = 0; nt < 12; nt++) acc[nt] = zero4;
#pragma unroll
            for (int kc = 0; kc < 6; kc++) {
#pragma unroll
                for (int nt = 0; nt < 12; nt++) {
                    const short8 bf = *(const short8*)(Ws + (nt * 16 + l16) * 200 + kc * 32 + (quad << 3));
                    acc[nt] = __builtin_amdgcn_mfma_f32_16x16x32_bf16(a[mi][kc], bf, acc[nt], 0, 0, 0);
                }
            }
            unsigned short* dst = Kb + (size_t)b * NPAD * CEMB;
#pragma unroll
            for (int nt = 0; nt < 12; nt++) {
#pragma unroll
                for (int r = 0; r < 4; r++) {
                    int m = mt * 16 + (quad << 2) + r;
                    dst[(size_t)m * CEMB + nt * 16 + l16] = f2bf(acc[nt][r]);
                }
            }
        }
        __syncthreads();
        // stage V weights (kvw rows 192..383)
        for (int i = tid; i < 4608; i += 512) {
            int r = i / 24, c8 = i - r * 24;
            *(short8*)(Ws + r * 200 + c8 * 8) = *(const short8*)(kvwb + (size_t)(192 + r) * CEMB + c8 * 8);
        }
        __syncthreads();
        // V pass (reuses held A-frags)
#pragma unroll
        for (int mi = 0; mi < 3; mi++) {
            int mt = wave + (mi << 3);
            if (mt >= 22) continue;
            f32x4 acc[12];
#pragma unroll
            for (int nt = 0; nt < 12; nt++) acc[nt] = zero4;
#pragma unroll
            for (int kc = 0; kc < 6; kc++) {
#pragma unroll
                for (int nt = 0; nt < 12; nt++) {
                    const short8 bf = *(const short8*)(Ws + (nt * 16 + l16) * 200 + kc * 32 + (quad << 3));
                    acc[nt] = __builtin_amdgcn_mfma_f32_16x16x32_bf16(a[mi][kc], bf, acc[nt], 0, 0, 0);
                }
            }
#pragma unroll
            for (int nt = 0; nt < 12; nt++) {
                int h = nt >> 1, d = ((nt & 1) << 4) + l16;
#pragma unroll
                for (int r = 0; r < 4; r++) {
                    int m = mt * 16 + (quad << 2) + r;
                    Vtb[(((size_t)b * NH + h) * 32 + d) * 360 + m] = f2bf(acc[nt][r]);
                }
            }
        }
    }
}

// ---------------- fused attention per (window b, head h) ----------------
// LDS (28160 B): Ks[352][40] only -> 4 blocks/CU (launch_bounds(512,8)).
// V^T plane (23 KB, read 24x/block) comes straight from L2. Softmax
// denominator in f32 (rp add-chain + quad shuffle reduce) -- the bf16
// MFMA-ones variant failed the absmax threshold (round-5 post-mortem).
// C-operands (bias+mask) prefetched one chunk ahead, converted off-path.
__global__ __launch_bounds__(512, 8)
void attn_kernel(const unsigned short* __restrict__ Qb, const unsigned short* __restrict__ Kb,
                 const unsigned short* __restrict__ Vtb,
                 const unsigned short* __restrict__ biasF, const unsigned short* __restrict__ maskF,
                 unsigned short* __restrict__ attnb) {
    extern __shared__ char smem[];
    unsigned short* Ks = (unsigned short*)smem;             // [352][40]

    const int tid = threadIdx.x;
    const int wave = tid >> 6, lane = tid & 63;
    const int quad = lane >> 4, l16 = lane & 15;
    const int q4 = quad << 2, q8 = quad << 3;
    // XCD-aware swizzle: physical p -> XCD p%8 owns 192 consecutive logical blocks;
    // logical order (w, b>>6, h): 24 consecutive blocks share one mask plane.
    const int p = blockIdx.x;
    const int L = (p & 7) * 192 + (p >> 3);
    const int w = L / 24, r_ = L - w * 24;
    const int b = (r_ / 6) * 64 + w;
    const int h = r_ - (r_ / 6) * 6;
    const f32x4 zero4 = {0.f, 0.f, 0.f, 0.f};

    // stage K (this head's 32 channels) into A-frag layout [key][40]
    for (int i = tid; i < 1408; i += 512) {
        int key = i >> 2, part = i & 3;
        *(short8*)(Ks + key * 40 + part * 8) =
            *(const short8*)(Kb + ((size_t)b * NPAD + key) * CEMB + h * 32 + part * 8);
    }
    __syncthreads();

    const unsigned short* Vp = Vtb + (size_t)(b * NH + h) * 32 * 360;   // L2-resident
    const unsigned short* bF = biasF + (size_t)h * FPLANE;
    const unsigned short* mF = maskF + (size_t)w * FPLANE;
    const int lane4 = lane << 2;

#pragma unroll
    for (int i = 0; i < 3; i++) {
        int mt = wave + (i << 3);
        if (mt >= 22) continue;             // wave-uniform, no barriers below
        // this wave's Q B-frag (loaded per i to cap register pressure)
        const short8 qa = *(const short8*)(Qb + ((size_t)b * NPAD + mt * 16 + l16) * CEMB + h * 32 + q8);
        float rp = 0.f;
        f32x4 o0 = zero4, o1 = zero4;
        int off = mt * 5632;                // (mt*11 + ch)*512 + t*256
        f32x4 c0c, c1c;
        {
            ushort4 bt0 = *(const ushort4*)(bF + off + lane4);
            ushort4 mk0 = *(const ushort4*)(mF + off + lane4);
            ushort4 bt1 = *(const ushort4*)(bF + off + 256 + lane4);
            ushort4 mk1 = *(const ushort4*)(mF + off + 256 + lane4);
            c0c[0] = bf2f(bt0.x) + bf2f(mk0.x); c0c[1] = bf2f(bt0.y) + bf2f(mk0.y);
            c0c[2] = bf2f(bt0.z) + bf2f(mk0.z); c0c[3] = bf2f(bt0.w) + bf2f(mk0.w);
            c1c[0] = bf2f(bt1.x) + bf2f(mk1.x); c1c[1] = bf2f(bt1.y) + bf2f(mk1.y);
            c1c[2] = bf2f(bt1.z) + bf2f(mk1.z); c1c[3] = bf2f(bt1.w) + bf2f(mk1.w);
        }
        for (int ch = 0; ch < 11; ch++) {
            const int kb_ = ch * 32;
            const int offn = (ch < 10) ? off + 512 : off;   // last iter: harmless reload
            ushort4 bt0n = *(const ushort4*)(bF + offn + lane4);
            ushort4 mk0n = *(const ushort4*)(mF + offn + lane4);
            ushort4 bt1n = *(const ushort4*)(bF + offn + 256 + lane4);
            ushort4 mk1n = *(const ushort4*)(mF + offn + 256 + lane4);
            f32x4 c0n, c1n;
            c0n[0] = bf2f(bt0n.x) + bf2f(mk0n.x); c0n[1] = bf2f(bt0n.y) + bf2f(mk0n.y);
            c0n[2] = bf2f(bt0n.z) + bf2f(mk0n.z); c0n[3] = bf2f(bt0n.w) + bf2f(mk0n.w);
            c1n[0] = bf2f(bt1n.x) + bf2f(mk1n.x); c1n[1] = bf2f(bt1n.y) + bf2f(mk1n.y);
            c1n[2] = bf2f(bt1n.z) + bf2f(mk1n.z); c1n[3] = bf2f(bt1n.w) + bf2f(mk1n.w);
            const short8 k0f = *(const short8*)(Ks + (kb_ + l16) * 40 + q8);
            const short8 k1f = *(const short8*)(Ks + (kb_ + 16 + l16) * 40 + q8);
            // S^T tiles: lane holds S[q=l16][key = kb_ + 16t + q4 + r] in s{t}[r]
            f32x4 s0 = __builtin_amdgcn_mfma_f32_16x16x32_bf16(k0f, qa, c0c, 0, 0, 0);
            f32x4 s1 = __builtin_amdgcn_mfma_f32_16x16x32_bf16(k1f, qa, c1c, 0, 0, 0);
            float p00 = __builtin_amdgcn_exp2f(s0[0]);
            float p01 = __builtin_amdgcn_exp2f(s0[1]);
            float p02 = __builtin_amdgcn_exp2f(s0[2]);
            float p03 = __builtin_amdgcn_exp2f(s0[3]);
            float p10 = __builtin_amdgcn_exp2f(s1[0]);
            float p11 = __builtin_amdgcn_exp2f(s1[1]);
            float p12 = __builtin_amdgcn_exp2f(s1[2]);
            float p13 = __builtin_amdgcn_exp2f(s1[3]);
            // f32 denominator (round-4 proven numerics; pad keys contribute 0)
            rp += ((p00 + p01) + (p02 + p03)) + ((p10 + p11) + (p12 + p13));
            // pack to bf16 pairs; 4x4 u32 cross-quad transpose via permlane swaps
            unsigned int e0 = cvt_pk_bf16(p00, p01);
            unsigned int e1 = cvt_pk_bf16(p02, p03);
            unsigned int e2 = cvt_pk_bf16(p10, p11);
            unsigned int e3 = cvt_pk_bf16(p12, p13);
            uint2v sa = __builtin_amdgcn_permlane32_swap(e0, e2, false, false);
            uint2v sb = __builtin_amdgcn_permlane32_swap(e1, e3, false, false);
            uint2v ta = __builtin_amdgcn_permlane16_swap(sa[0], sa[1], false, false);
            uint2v tb = __builtin_amdgcn_permlane16_swap(sb[0], sb[1], false, false);
            // PV A-frag: A[q=l16][key kb_ + q8 + j], j=0..7
            const short8 pa = __builtin_bit_cast(short8, (uint4v){ta[0], tb[0], ta[1], tb[1]});
            const short8 v0 = *(const short8*)(Vp + l16 * 360 + kb_ + q8);
            const short8 v1 = *(const short8*)(Vp + (16 + l16) * 360 + kb_ + q8);
            o0 = __builtin_amdgcn_mfma_f32_16x16x32_bf16(pa, v0, o0, 0, 0, 0);
            o1 = __builtin_amdgcn_mfma_f32_16x16x32_bf16(pa, v1, o1, 0, 0, 0);
            c0c = c0n; c1c = c1n; off = offn;
        }
        // rp holds this quad's partial key-sum for q=l16; reduce across quads
        rp += __shfl_xor(rp, 16);
        rp += __shfl_xor(rp, 32);
        float inv = 1.f / rp;               // inverse row-sum for q = mt*16 + l16
#pragma unroll
        for (int r = 0; r < 4; r++) {
            // output row n = mt*16 + q4 + r: fetch its inv from lane l16 = q4+r
            float invr = __shfl(inv, (lane & 48) | (q4 + r));
            int n = mt * 16 + q4 + r;
            if (n < NTOK) {
                size_t base = ((size_t)b * NTOK + n) * CEMB + h * 32;
                attnb[base + l16] = f2bf(o0[r] * invr);
                attnb[base + 16 + l16] = f2bf(o1[r] * invr);
            }
        }
    }
}

// ---------------- output projection: out = attn @ proj_w^T + proj_b ----------------
// Weights staged in LDS ([192][200], 76.8 KB); 8 M-tiles per block (1/wave).
__global__ __launch_bounds__(512, 2)
void proj_kernel(const unsigned short* __restrict__ attnb, const unsigned short* __restrict__ pwb,
                 const float* __restrict__ proj_b, float* __restrict__ out) {
    extern __shared__ char smem[];
    unsigned short* Ws = (unsigned short*)smem;   // [192][200] padded
    const int tid = threadIdx.x;
    const int wave = tid >> 6, lane = tid & 63;
    const int quad = lane >> 4, l16 = lane & 15;
    for (int i = tid; i < 4608; i += 512) {
        int r = i / 24, c8 = i - r * 24;
        *(short8*)(Ws + r * 200 + c8 * 8) = *(const short8*)(pwb + (size_t)r * CEMB + c8 * 8);
    }
    float pb[12];
#pragma unroll
    for (int nt = 0; nt < 12; nt++) pb[nt] = proj_b[nt * 16 + l16];
    __syncthreads();

    const int mt = blockIdx.x * 8 + wave;   // 686*8 = 5488 exact
    const f32x4 zero4 = {0.f, 0.f, 0.f, 0.f};
    f32x4 acc[12];
#pragma unroll
    for (int nt = 0; nt < 12; nt++) acc[nt] = zero4;
#pragma unroll
    for (int ks = 0; ks < 6; ks++) {
        const short8 a = *(const short8*)(attnb + ((size_t)mt * 16 + l16) * CEMB + ks * 32 + (quad << 3));
#pragma unroll
        for (int nt = 0; nt < 12; nt++) {
            const short8 bfrag = *(const short8*)(Ws + (nt * 16 + l16) * 200 + ks * 32 + (quad << 3));
            acc[nt] = __builtin_amdgcn_mfma_f32_16x16x32_bf16(a, bfrag, acc[nt], 0, 0, 0);
        }
    }
#pragma unroll
    for (int nt = 0; nt < 12; nt++) {
#pragma unroll
        for (int r = 0; r < 4; r++) {
            int m = mt * 16 + (quad << 2) + r;
            out[(size_t)m * CEMB + nt * 16 + l16] = acc[nt][r] + pb[nt];
        }
    }
}

// ---------------- launch ----------------
extern "C" void kernel_launch(void* const* d_in, const int* in_sizes, int n_in,
                              void* d_out, int out_size, void* d_ws, size_t ws_size,
                              hipStream_t stream) {
    (void)in_sizes; (void)n_in; (void)out_size; (void)ws_size;
    const float* x_in    = (const float*)d_in[0];
    const float* x_cross = (const float*)d_in[1];
    const float* mask    = (const float*)d_in[2];
    const float* q_w     = (const float*)d_in[3];
    const float* kv_w    = (const float*)d_in[4];
    const float* proj_w  = (const float*)d_in[5];
    const float* proj_b  = (const float*)d_in[6];
    const float* btab    = (const float*)d_in[7];
    const int*   rel     = (const int*)d_in[8];
    float* out = (float*)d_out;
    char* ws = (char*)d_ws;

    // ws layout (bytes), total 155,955,200:
    unsigned short* qwb   = (unsigned short*)(ws + 0);           //     73,728
    unsigned short* kvwb  = (unsigned short*)(ws + 73728);       //    147,456
    unsigned short* pwb   = (unsigned short*)(ws + 221184);      //     73,728
    unsigned short* biasF = (unsigned short*)(ws + 294912);      //  1,486,848
    unsigned short* maskF = (unsigned short*)(ws + 1781760);     // 15,859,712
    unsigned short* attnb = (unsigned short*)(ws + 17641472);    // 33,718,272
    unsigned short* Qb    = (unsigned short*)(ws + 51359744);    // 34,603,008
    unsigned short* Kb    = (unsigned short*)(ws + 85962752);    // 34,603,008
    unsigned short* Vtb   = (unsigned short*)(ws + 120565760);   // 35,389,440

    prep_wb<<<1304, 256, 0, stream>>>(q_w, kv_w, proj_w, btab, rel, qwb, kvwb, pwb, biasF);
    prep_maskF<<<7744, 256, 0, stream>>>(mask, maskF);
    qkv_kernel<<<2 * NB, 512, 76800, stream>>>(x_in, x_cross, qwb, kvwb, Qb, Kb, Vtb);
    attn_kernel<<<NB * NH, 512, 28160, stream>>>(Qb, Kb, Vtb, biasF, maskF, attnb);
    proj_kernel<<<686, 512, 76800, stream>>>(attnb, pwb, proj_b, out);
}

// Round 7
// 368.440 us; speedup vs baseline: 1.1009x; 1.1009x over previous
//
#include <hip/hip_runtime.h>

// Problem constants
#define NTOK 343   // tokens per window (7*7*7)
#define NPAD 352   // 22 * 16
#define CEMB 192
#define NH   6
#define HD   32
#define NB   256
#define NWIN 64
#define FPLANE 123904   // fragment-plane stride in shorts: 22*11*2*64*4

typedef __attribute__((ext_vector_type(8))) short short8;   // 8 x bf16 bits
typedef __attribute__((ext_vector_type(4))) float f32x4;
typedef __attribute__((ext_vector_type(4))) unsigned int uint4v;
typedef __attribute__((ext_vector_type(2))) unsigned int uint2v;

__device__ __forceinline__ unsigned short f2bf(float f) {
    unsigned int u = __builtin_bit_cast(unsigned int, f);
    u += 0x7fffu + ((u >> 16) & 1u);          // round-to-nearest-even
    return (unsigned short)(u >> 16);
}
__device__ __forceinline__ float bf2f(unsigned short h) {
    unsigned int u = ((unsigned int)h) << 16;
    return __builtin_bit_cast(float, u);
}
__device__ __forceinline__ short8 pack8(float4 f0, float4 f1) {
    short8 r;
    r[0] = (short)f2bf(f0.x); r[1] = (short)f2bf(f0.y);
    r[2] = (short)f2bf(f0.z); r[3] = (short)f2bf(f0.w);
    r[4] = (short)f2bf(f1.x); r[5] = (short)f2bf(f1.y);
    r[6] = (short)f2bf(f1.z); r[7] = (short)f2bf(f1.w);
    return r;
}
__device__ __forceinline__ unsigned int cvt_pk_bf16(float lo, float hi) {
    unsigned int r;
    asm("v_cvt_pk_bf16_f32 %0, %1, %2" : "=v"(r) : "v"(lo), "v"(hi));
    return r;
}

#define LOG2E 1.4426950408889634f

// ---------------- prep: weights -> bf16 AND biasF fragments (merged) ----------------
// blocks 0..575: weights (scale*log2e folded into qw)
// blocks 576..1303: biasF[h][mt][ch][t][lane][r] in MFMA-fragment order
__global__ void prep_wb(const float* __restrict__ qw, const float* __restrict__ kvw,
                        const float* __restrict__ pw, const float* __restrict__ table,
                        const int* __restrict__ rel,
                        unsigned short* __restrict__ qwb, unsigned short* __restrict__ kvwb,
                        unsigned short* __restrict__ pwb, unsigned short* __restrict__ biasF) {
    if (blockIdx.x < 576) {
        const float scale = 0.17677669529663689f * LOG2E;   // 32^-0.5 * log2(e)
        int idx = blockIdx.x * 256 + threadIdx.x;
        if (idx < 36864)        qwb[idx] = f2bf(qw[idx] * scale);
        else if (idx < 110592)  kvwb[idx - 36864] = f2bf(kvw[idx - 36864]);
        else if (idx < 147456)  pwb[idx - 110592] = f2bf(pw[idx - 110592]);
    } else {
        int idx = (blockIdx.x - 576) * 256 + threadIdx.x;   // 6*22*11*2*64 = 728*256 exact
        int lane = idx & 63;
        int rest = idx >> 6;
        int t = rest & 1; rest >>= 1;
        int ch = rest % 11; rest /= 11;
        int mt = rest % 22; int h = rest / 22;
        int q = mt * 16 + (lane & 15);
        int k0 = ch * 32 + t * 16 + ((lane >> 4) << 2);
        ushort4 out;
#pragma unroll
        for (int r = 0; r < 4; r++) {
            int k = k0 + r;
            float v = (q < NTOK && k < NTOK) ? table[rel[q * NTOK + k] * NH + h] * LOG2E : 0.f;
            ((unsigned short*)&out)[r] = f2bf(v);
        }
        *(ushort4*)(biasF + (size_t)idx * 4) = out;
    }
}

// ---------------- prep: maskF in MFMA-fragment order; pad keys = -60000 ----------------
__global__ void prep_maskF(const float* __restrict__ mask, unsigned short* __restrict__ maskF) {
    int idx = blockIdx.x * 256 + threadIdx.x;       // 64*22*11*2*64 = 7744*256 exact
    int lane = idx & 63;
    int rest = idx >> 6;
    int t = rest & 1; rest >>= 1;
    int ch = rest % 11; rest /= 11;
    int mt = rest % 22; int w = rest / 22;
    int q = mt * 16 + (lane & 15);
    int k0 = ch * 32 + t * 16 + ((lane >> 4) << 2);
    ushort4 out;
#pragma unroll
    for (int r = 0; r < 4; r++) {
        int k = k0 + r;
        float v;
        if (k >= NTOK) v = -60000.f;                 // pad key: exp2 -> 0, no branch in attn
        else if (q < NTOK) v = mask[((size_t)w * NTOK + q) * NTOK + k] * LOG2E;
        else v = 0.f;                                // pad q rows: stores are guarded anyway
        ((unsigned short*)&out)[r] = f2bf(v);
    }
    *(ushort4*)(maskF + (size_t)idx * 4) = out;
}

// ---------------- merged QKV projection GEMM ----------------
// 512 blocks: gid 0..255 -> Q for b=gid; gid 256..511 -> K+V for b=gid-256.
// Sequential dispatch puts one Q block + one KV block per CU (2 blocks/CU,
// 76.8 KB LDS each) instead of two serial 1-block/CU launches.
__global__ __launch_bounds__(512, 2)
void qkv_kernel(const float* __restrict__ x_in, const float* __restrict__ x_cross,
                const unsigned short* __restrict__ qwb, const unsigned short* __restrict__ kvwb,
                unsigned short* __restrict__ Qb, unsigned short* __restrict__ Kb,
                unsigned short* __restrict__ Vtb) {
    extern __shared__ char smem[];
    unsigned short* Ws = (unsigned short*)smem;      // [192][200] padded
    const int tid = threadIdx.x;
    const int wave = tid >> 6, lane = tid & 63;
    const int quad = lane >> 4, l16 = lane & 15;
    const f32x4 zero4 = {0.f, 0.f, 0.f, 0.f};

    if (blockIdx.x < NB) {
        // ---------------- Q path ----------------
        const int b = blockIdx.x;
        for (int i = tid; i < 4608; i += 512) {
            int r = i / 24, c8 = i - r * 24;
            *(short8*)(Ws + r * 200 + c8 * 8) = *(const short8*)(qwb + (size_t)r * CEMB + c8 * 8);
        }
        __syncthreads();
        for (int mi = 0; mi < 3; mi++) {
            int mt = wave + (mi << 3);
            if (mt >= 22) continue;            // wave-uniform
            int row = mt * 16 + l16;
            f32x4 acc[12];
#pragma unroll
            for (int nt = 0; nt < 12; nt++) acc[nt] = zero4;
#pragma unroll
            for (int kc = 0; kc < 6; kc++) {
                short8 a = {};
                if (row < NTOK) {
                    const float* xp = x_in + ((size_t)b * NTOK + row) * CEMB + kc * 32 + (quad << 3);
                    a = pack8(*(const float4*)xp, *(const float4*)(xp + 4));
                }
#pragma unroll
                for (int nt = 0; nt < 12; nt++) {
                    const short8 bf = *(const short8*)(Ws + (nt * 16 + l16) * 200 + kc * 32 + (quad << 3));
                    acc[nt] = __builtin_amdgcn_mfma_f32_16x16x32_bf16(a, bf, acc[nt], 0, 0, 0);
                }
            }
            unsigned short* dst = Qb + (size_t)b * NPAD * CEMB;
#pragma unroll
            for (int nt = 0; nt < 12; nt++) {
#pragma unroll
                for (int r = 0; r < 4; r++) {
                    int m = mt * 16 + (quad << 2) + r;
                    dst[(size_t)m * CEMB + nt * 16 + l16] = f2bf(acc[nt][r]);
                }
            }
        }
    } else {
        // ---------------- K+V path (x_cross read once, A-frags held in regs) ----------------
        const int b = blockIdx.x - NB;
        for (int i = tid; i < 4608; i += 512) {
            int r = i / 24, c8 = i - r * 24;
            *(short8*)(Ws + r * 200 + c8 * 8) = *(const short8*)(kvwb + (size_t)r * CEMB + c8 * 8);
        }
        short8 a[3][6];
#pragma unroll
        for (int mi = 0; mi < 3; mi++) {
            int mt = wave + (mi << 3);
            int row = mt * 16 + l16;
#pragma unroll
            for (int kc = 0; kc < 6; kc++) {
                a[mi][kc] = (short8){};
                if (mt < 22 && row < NTOK) {
                    const float* xp = x_cross + ((size_t)b * NTOK + row) * CEMB + kc * 32 + (quad << 3);
                    a[mi][kc] = pack8(*(const float4*)xp, *(const float4*)(xp + 4));
                }
            }
        }
        __syncthreads();
        // K pass
#pragma unroll
        for (int mi = 0; mi < 3; mi++) {
            int mt = wave + (mi << 3);
            if (mt >= 22) continue;
            f32x4 acc[12];
#pragma unroll
            for (int nt = 0; nt < 12; nt++) acc[nt] = zero4;
#pragma unroll
            for (int kc = 0; kc < 6; kc++) {
#pragma unroll
                for (int nt = 0; nt < 12; nt++) {
                    const short8 bf = *(const short8*)(Ws + (nt * 16 + l16) * 200 + kc * 32 + (quad << 3));
                    acc[nt] = __builtin_amdgcn_mfma_f32_16x16x32_bf16(a[mi][kc], bf, acc[nt], 0, 0, 0);
                }
            }
            unsigned short* dst = Kb + (size_t)b * NPAD * CEMB;
#pragma unroll
            for (int nt = 0; nt < 12; nt++) {
#pragma unroll
                for (int r = 0; r < 4; r++) {
                    int m = mt * 16 + (quad << 2) + r;
                    dst[(size_t)m * CEMB + nt * 16 + l16] = f2bf(acc[nt][r]);
                }
            }
        }
        __syncthreads();
        // stage V weights (kvw rows 192..383)
        for (int i = tid; i < 4608; i += 512) {
            int r = i / 24, c8 = i - r * 24;
            *(short8*)(Ws + r * 200 + c8 * 8) = *(const short8*)(kvwb + (size_t)(192 + r) * CEMB + c8 * 8);
        }
        __syncthreads();
        // V pass (reuses held A-frags)
#pragma unroll
        for (int mi = 0; mi < 3; mi++) {
            int mt = wave + (mi << 3);
            if (mt >= 22) continue;
            f32x4 acc[12];
#pragma unroll
            for (int nt = 0; nt < 12; nt++) acc[nt] = zero4;
#pragma unroll
            for (int kc = 0; kc < 6; kc++) {
#pragma unroll
                for (int nt = 0; nt < 12; nt++) {
                    const short8 bf = *(const short8*)(Ws + (nt * 16 + l16) * 200 + kc * 32 + (quad << 3));
                    acc[nt] = __builtin_amdgcn_mfma_f32_16x16x32_bf16(a[mi][kc], bf, acc[nt], 0, 0, 0);
                }
            }
#pragma unroll
            for (int nt = 0; nt < 12; nt++) {
                int h = nt >> 1, d = ((nt & 1) << 4) + l16;
#pragma unroll
                for (int r = 0; r < 4; r++) {
                    int m = mt * 16 + (quad << 2) + r;
                    Vtb[(((size_t)b * NH + h) * 32 + d) * 360 + m] = f2bf(acc[nt][r]);
                }
            }
        }
    }
}

// ---------------- fused attention per (window b, head h) ----------------
// LDS (51200 B): Ks[352][40] @0, Vt[32][360] @28160. 3 blocks/CU.
// Round-6 lesson: V^T must be LDS-staged -- the 23 KB plane x ~128 concurrent
// blocks/XCD thrashes L2 (FETCH 70->129 MB, attn 91->143 us). Swapped QK^T;
// bias+mask as MFMA C operand (fragment-ordered tables, pad keys = -60000);
// f32 softmax denominator (bf16 variant fails absmax); permlane transpose;
// XCD swizzle. unroll 2 on ch loop for cross-chunk ILP.
__global__ __launch_bounds__(512, 6)
void attn_kernel(const unsigned short* __restrict__ Qb, const unsigned short* __restrict__ Kb,
                 const unsigned short* __restrict__ Vtb,
                 const unsigned short* __restrict__ biasF, const unsigned short* __restrict__ maskF,
                 unsigned short* __restrict__ attnb) {
    extern __shared__ char smem[];
    unsigned short* Ks = (unsigned short*)smem;             // [352][40]
    unsigned short* Vt = (unsigned short*)(smem + 28160);   // [32][360]

    const int tid = threadIdx.x;
    const int wave = tid >> 6, lane = tid & 63;
    const int quad = lane >> 4, l16 = lane & 15;
    const int q4 = quad << 2, q8 = quad << 3;
    // XCD-aware swizzle: physical p -> XCD p%8 owns 192 consecutive logical blocks;
    // logical order (w, b>>6, h): 24 consecutive blocks share one mask plane.
    const int p = blockIdx.x;
    const int L = (p & 7) * 192 + (p >> 3);
    const int w = L / 24, r_ = L - w * 24;
    const int b = (r_ / 6) * 64 + w;
    const int h = r_ - (r_ / 6) * 6;
    const f32x4 zero4 = {0.f, 0.f, 0.f, 0.f};

    // stage K (this head's 32 channels) into A-frag layout [key][40]
    for (int i = tid; i < 1408; i += 512) {
        int key = i >> 2, part = i & 3;
        *(short8*)(Ks + key * 40 + part * 8) =
            *(const short8*)(Kb + ((size_t)b * NPAD + key) * CEMB + h * 32 + part * 8);
    }
    // stage V^T (contiguous copy of this (b,h) plane)
    const unsigned short* vsrc = Vtb + (size_t)(b * NH + h) * 32 * 360;
    for (int i = tid; i < 1440; i += 512) {
        *(short8*)(Vt + i * 8) = *(const short8*)(vsrc + i * 8);
    }
    // per-wave Q B-frags straight from global
    short8 qa[3] = {};
#pragma unroll
    for (int i = 0; i < 3; i++) {
        int mt = wave + (i << 3);
        if (mt < 22)
            qa[i] = *(const short8*)(Qb + ((size_t)b * NPAD + mt * 16 + l16) * CEMB + h * 32 + q8);
    }
    __syncthreads();

    const unsigned short* bF = biasF + (size_t)h * FPLANE;
    const unsigned short* mF = maskF + (size_t)w * FPLANE;
    const int lane4 = lane << 2;
#pragma unroll
    for (int i = 0; i < 3; i++) {
        int mt = wave + (i << 3);
        if (mt >= 22) continue;             // wave-uniform, no barriers below
        float rp = 0.f;
        f32x4 o0 = zero4, o1 = zero4;
        int off = mt * 5632;                // (mt*11 + ch)*512 + t*256
        f32x4 c0c, c1c;
        {
            ushort4 bt0 = *(const ushort4*)(bF + off + lane4);
            ushort4 mk0 = *(const ushort4*)(mF + off + lane4);
            ushort4 bt1 = *(const ushort4*)(bF + off + 256 + lane4);
            ushort4 mk1 = *(const ushort4*)(mF + off + 256 + lane4);
            c0c[0] = bf2f(bt0.x) + bf2f(mk0.x); c0c[1] = bf2f(bt0.y) + bf2f(mk0.y);
            c0c[2] = bf2f(bt0.z) + bf2f(mk0.z); c0c[3] = bf2f(bt0.w) + bf2f(mk0.w);
            c1c[0] = bf2f(bt1.x) + bf2f(mk1.x); c1c[1] = bf2f(bt1.y) + bf2f(mk1.y);
            c1c[2] = bf2f(bt1.z) + bf2f(mk1.z); c1c[3] = bf2f(bt1.w) + bf2f(mk1.w);
        }
#pragma unroll 2
        for (int ch = 0; ch < 11; ch++) {
            const int kb_ = ch * 32;
            const int offn = (ch < 10) ? off + 512 : off;   // last iter: harmless reload
            ushort4 bt0n = *(const ushort4*)(bF + offn + lane4);
            ushort4 mk0n = *(const ushort4*)(mF + offn + lane4);
            ushort4 bt1n = *(const ushort4*)(bF + offn + 256 + lane4);
            ushort4 mk1n = *(const ushort4*)(mF + offn + 256 + lane4);
            f32x4 c0n, c1n;
            c0n[0] = bf2f(bt0n.x) + bf2f(mk0n.x); c0n[1] = bf2f(bt0n.y) + bf2f(mk0n.y);
            c0n[2] = bf2f(bt0n.z) + bf2f(mk0n.z); c0n[3] = bf2f(bt0n.w) + bf2f(mk0n.w);
            c1n[0] = bf2f(bt1n.x) + bf2f(mk1n.x); c1n[1] = bf2f(bt1n.y) + bf2f(mk1n.y);
            c1n[2] = bf2f(bt1n.z) + bf2f(mk1n.z); c1n[3] = bf2f(bt1n.w) + bf2f(mk1n.w);
            const short8 k0f = *(const short8*)(Ks + (kb_ + l16) * 40 + q8);
            const short8 k1f = *(const short8*)(Ks + (kb_ + 16 + l16) * 40 + q8);
            // S^T tiles: lane holds S[q=l16][key = kb_ + 16t + q4 + r] in s{t}[r]
            f32x4 s0 = __builtin_amdgcn_mfma_f32_16x16x32_bf16(k0f, qa[i], c0c, 0, 0, 0);
            f32x4 s1 = __builtin_amdgcn_mfma_f32_16x16x32_bf16(k1f, qa[i], c1c, 0, 0, 0);
            float p00 = __builtin_amdgcn_exp2f(s0[0]);
            float p01 = __builtin_amdgcn_exp2f(s0[1]);
            float p02 = __builtin_amdgcn_exp2f(s0[2]);
            float p03 = __builtin_amdgcn_exp2f(s0[3]);
            float p10 = __builtin_amdgcn_exp2f(s1[0]);
            float p11 = __builtin_amdgcn_exp2f(s1[1]);
            float p12 = __builtin_amdgcn_exp2f(s1[2]);
            float p13 = __builtin_amdgcn_exp2f(s1[3]);
            // f32 denominator (proven numerics; pad keys contribute 0)
            rp += ((p00 + p01) + (p02 + p03)) + ((p10 + p11) + (p12 + p13));
            // pack to bf16 pairs; 4x4 u32 cross-quad transpose via permlane swaps
            unsigned int e0 = cvt_pk_bf16(p00, p01);
            unsigned int e1 = cvt_pk_bf16(p02, p03);
            unsigned int e2 = cvt_pk_bf16(p10, p11);
            unsigned int e3 = cvt_pk_bf16(p12, p13);
            uint2v sa = __builtin_amdgcn_permlane32_swap(e0, e2, false, false);
            uint2v sb = __builtin_amdgcn_permlane32_swap(e1, e3, false, false);
            uint2v ta = __builtin_amdgcn_permlane16_swap(sa[0], sa[1], false, false);
            uint2v tb = __builtin_amdgcn_permlane16_swap(sb[0], sb[1], false, false);
            // PV A-frag: A[q=l16][key kb_ + q8 + j], j=0..7
            const short8 pa = __builtin_bit_cast(short8, (uint4v){ta[0], tb[0], ta[1], tb[1]});
            const short8 v0 = *(const short8*)(Vt + l16 * 360 + kb_ + q8);
            const short8 v1 = *(const short8*)(Vt + (16 + l16) * 360 + kb_ + q8);
            o0 = __builtin_amdgcn_mfma_f32_16x16x32_bf16(pa, v0, o0, 0, 0, 0);
            o1 = __builtin_amdgcn_mfma_f32_16x16x32_bf16(pa, v1, o1, 0, 0, 0);
            c0c = c0n; c1c = c1n; off = offn;
        }
        // rp holds this quad's partial key-sum for q=l16; reduce across quads
        rp += __shfl_xor(rp, 16);
        rp += __shfl_xor(rp, 32);
        float inv = 1.f / rp;               // inverse row-sum for q = mt*16 + l16
#pragma unroll
        for (int r = 0; r < 4; r++) {
            // output row n = mt*16 + q4 + r: fetch its inv from lane l16 = q4+r
            float invr = __shfl(inv, (lane & 48) | (q4 + r));
            int n = mt * 16 + q4 + r;
            if (n < NTOK) {
                size_t base = ((size_t)b * NTOK + n) * CEMB + h * 32;
                attnb[base + l16] = f2bf(o0[r] * invr);
                attnb[base + 16 + l16] = f2bf(o1[r] * invr);
            }
        }
    }
}

// ---------------- output projection: out = attn @ proj_w^T + proj_b ----------------
// Weights staged in LDS ([192][200], 76.8 KB); 8 M-tiles per block (1/wave).
__global__ __launch_bounds__(512, 2)
void proj_kernel(const unsigned short* __restrict__ attnb, const unsigned short* __restrict__ pwb,
                 const float* __restrict__ proj_b, float* __restrict__ out) {
    extern __shared__ char smem[];
    unsigned short* Ws = (unsigned short*)smem;   // [192][200] padded
    const int tid = threadIdx.x;
    const int wave = tid >> 6, lane = tid & 63;
    const int quad = lane >> 4, l16 = lane & 15;
    for (int i = tid; i < 4608; i += 512) {
        int r = i / 24, c8 = i - r * 24;
        *(short8*)(Ws + r * 200 + c8 * 8) = *(const short8*)(pwb + (size_t)r * CEMB + c8 * 8);
    }
    float pb[12];
#pragma unroll
    for (int nt = 0; nt < 12; nt++) pb[nt] = proj_b[nt * 16 + l16];
    __syncthreads();

    const int mt = blockIdx.x * 8 + wave;   // 686*8 = 5488 exact
    const f32x4 zero4 = {0.f, 0.f, 0.f, 0.f};
    f32x4 acc[12];
#pragma unroll
    for (int nt = 0; nt < 12; nt++) acc[nt] = zero4;
#pragma unroll
    for (int ks = 0; ks < 6; ks++) {
        const short8 a = *(const short8*)(attnb + ((size_t)mt * 16 + l16) * CEMB + ks * 32 + (quad << 3));
#pragma unroll
        for (int nt = 0; nt < 12; nt++) {
            const short8 bfrag = *(const short8*)(Ws + (nt * 16 + l16) * 200 + ks * 32 + (quad << 3));
            acc[nt] = __builtin_amdgcn_mfma_f32_16x16x32_bf16(a, bfrag, acc[nt], 0, 0, 0);
        }
    }
#pragma unroll
    for (int nt = 0; nt < 12; nt++) {
#pragma unroll
        for (int r = 0; r < 4; r++) {
            int m = mt * 16 + (quad << 2) + r;
            out[(size_t)m * CEMB + nt * 16 + l16] = acc[nt][r] + pb[nt];
        }
    }
}

// ---------------- launch ----------------
extern "C" void kernel_launch(void* const* d_in, const int* in_sizes, int n_in,
                              void* d_out, int out_size, void* d_ws, size_t ws_size,
                              hipStream_t stream) {
    (void)in_sizes; (void)n_in; (void)out_size; (void)ws_size;
    const float* x_in    = (const float*)d_in[0];
    const float* x_cross = (const float*)d_in[1];
    const float* mask    = (const float*)d_in[2];
    const float* q_w     = (const float*)d_in[3];
    const float* kv_w    = (const float*)d_in[4];
    const float* proj_w  = (const float*)d_in[5];
    const float* proj_b  = (const float*)d_in[6];
    const float* btab    = (const float*)d_in[7];
    const int*   rel     = (const int*)d_in[8];
    float* out = (float*)d_out;
    char* ws = (char*)d_ws;

    // ws layout (bytes), total 155,955,200:
    unsigned short* qwb   = (unsigned short*)(ws + 0);           //     73,728
    unsigned short* kvwb  = (unsigned short*)(ws + 73728);       //    147,456
    unsigned short* pwb   = (unsigned short*)(ws + 221184);      //     73,728
    unsigned short* biasF = (unsigned short*)(ws + 294912);      //  1,486,848
    unsigned short* maskF = (unsigned short*)(ws + 1781760);     // 15,859,712
    unsigned short* attnb = (unsigned short*)(ws + 17641472);    // 33,718,272
    unsigned short* Qb    = (unsigned short*)(ws + 51359744);    // 34,603,008
    unsigned short* Kb    = (unsigned short*)(ws + 85962752);    // 34,603,008
    unsigned short* Vtb   = (unsigned short*)(ws + 120565760);   // 35,389,440

    prep_wb<<<1304, 256, 0, stream>>>(q_w, kv_w, proj_w, btab, rel, qwb, kvwb, pwb, biasF);
    prep_maskF<<<7744, 256, 0, stream>>>(mask, maskF);
    qkv_kernel<<<2 * NB, 512, 76800, stream>>>(x_in, x_cross, qwb, kvwb, Qb, Kb, Vtb);
    attn_kernel<<<NB * NH, 512, 51200, stream>>>(Qb, Kb, Vtb, biasF, maskF, attnb);
    proj_kernel<<<686, 512, 76800, stream>>>(attnb, pwb, proj_b, out);
}